// Round 13
// baseline (101.828 us; speedup 1.0000x reference)
//
#include <hip/hip_runtime.h>

constexpr int Bn = 8, Tn = 4096, Dn = 512, Hn = 512;
constexpr int Mn = Bn * Tn;            // 32768 rows
constexpr int CH = 64, NC = Tn / CH;   // 64 chunks of 64 steps

typedef __attribute__((ext_vector_type(8))) short s8v;       // 8 bf16
typedef __attribute__((ext_vector_type(4))) float f4v;       // MFMA acc
typedef __attribute__((ext_vector_type(8))) _Float16 h8v;    // 16B granule: a[0..3], b[0..3]
typedef unsigned short ushort_t;

typedef __attribute__((address_space(1))) const void gv_t;   // global src for load_lds
typedef __attribute__((address_space(3))) void lv_t;         // LDS dst for load_lds

__device__ __forceinline__ short f2bf(float f) {
  unsigned u = __float_as_uint(f);
  u = (u + 0x7fffu + ((u >> 16) & 1u)) >> 16;   // RNE
  return (short)u;
}

// fp32 [rows][512] -> bf16 tiles of 128 rows x 32 k in MFMA-fragment order.
// Tile lb = rt*16 + kt; chunk c = (r>>4)*64 + k8*16 + (r&15), 16B each.
__global__ __launch_bounds__(256) void convert_x(
    const float* __restrict__ X, ushort_t* __restrict__ Xb) {
  int lb = blockIdx.x, tid = threadIdx.x;
  const float* tsrc = X + ((size_t)(lb >> 4) * 128) * Dn + (lb & 15) * 32;
#pragma unroll
  for (int p = 0; p < 2; p++) {
    int idx = tid + p * 256;
    int r = idx >> 2, k8 = idx & 3;
    const float4* sv = reinterpret_cast<const float4*>(tsrc + (size_t)r * Dn + k8 * 8);
    float4 f0 = sv[0], f1 = sv[1];
    s8v v;
    v[0] = f2bf(f0.x); v[1] = f2bf(f0.y); v[2] = f2bf(f0.z); v[3] = f2bf(f0.w);
    v[4] = f2bf(f1.x); v[5] = f2bf(f1.y); v[6] = f2bf(f1.z); v[7] = f2bf(f1.w);
    int c = (r >> 4) * 64 + k8 * 16 + (r & 15);
    *reinterpret_cast<s8v*>(&Xb[((size_t)lb * 512 + c) * 8]) = v;
  }
}

// Same for W. Blocks [0,64) = Wz, [64,128) = Wh.
__global__ __launch_bounds__(256) void convert_w(
    const float* __restrict__ Wz, const float* __restrict__ Wh,
    ushort_t* __restrict__ Wzb, ushort_t* __restrict__ Whb) {
  int bx = blockIdx.x, tid = threadIdx.x;
  const float* src;
  ushort_t* dst;
  int lb;
  if (bx < 64) { src = Wz; dst = Wzb; lb = bx; }
  else         { src = Wh; dst = Whb; lb = bx - 64; }
  const float* tsrc = src + ((size_t)(lb >> 4) * 128) * Dn + (lb & 15) * 32;
#pragma unroll
  for (int p = 0; p < 2; p++) {
    int idx = tid + p * 256;
    int r = idx >> 2, k8 = idx & 3;
    const float4* sv = reinterpret_cast<const float4*>(tsrc + (size_t)r * Dn + k8 * 8);
    float4 f0 = sv[0], f1 = sv[1];
    s8v v;
    v[0] = f2bf(f0.x); v[1] = f2bf(f0.y); v[2] = f2bf(f0.z); v[3] = f2bf(f0.w);
    v[4] = f2bf(f1.x); v[5] = f2bf(f1.y); v[6] = f2bf(f1.z); v[7] = f2bf(f1.w);
    int c = (r >> 4) * 64 + k8 * 16 + (r & 15);
    *reinterpret_cast<s8v*>(&dst[((size_t)lb * 512 + c) * 8]) = v;
  }
}

// W-stationary barrier-free dual GEMM + activations + chunk summaries.
// OCCUPANCY-FIRST variant: 16 waves/block (1024 thr), wave = 64 rows x 32
// cols dual -> acc 64 AGPR; VGPR budget ~62 -> total <=128 regs/wave ->
// 4 waves/SIMD (vs 2 in all prior variants). Full W panel (64 cols, K=512,
// z+h = 128KB) LDS-resident; K-loop barrier-free: W broadcast ds_read,
// X reg-direct from pre-swizzled Xb with 2-slot static prefetch.
__global__ __launch_bounds__(1024, 4) void gemm_act(
    const ushort_t* __restrict__ Xb, const ushort_t* __restrict__ Wzb,
    const ushort_t* __restrict__ Whb,
    const float* __restrict__ bzp, const float* __restrict__ bhp,
    h8v* __restrict__ cab, float* __restrict__ cA, float* __restrict__ cB) {
  __shared__ __align__(16) ushort_t lds[65536];   // 128 KB: Wz [0,32K), Wh [32K,64K) halves

  int tid = threadIdx.x, lane = tid & 63, wid = tid >> 6;
  int wr = wid >> 1, wc = wid & 1;              // 8 row-groups x 2 col-groups

  // XCD-affinity: XCD x owns mt in [8x, 8x+8); 8 panels of one mt adjacent.
  int o = blockIdx.x;
  int loc = o >> 3;
  int mt = (o & 7) * 8 + (loc >> 3);            // [0,64)  M-tile of 512 rows
  int p = loc & 7;                              // [0,8)   64-col H-panel

  // ---- stage W panel: 32 regions x 4KB; region r = kt (Wz) / 16+kt (Wh) ----
  const ushort_t* wzp = Wzb + ((size_t)(p >> 1) * 16) * 4096 + (p & 1) * 2048;
  const ushort_t* whp = Whb + ((size_t)(p >> 1) * 16) * 4096 + (p & 1) * 2048;
#pragma unroll
  for (int q = 0; q < 8; q++) {
    int idx = q * 1024 + tid;                   // 16B chunk id [0,8192)
    int r = idx >> 8, cc = idx & 255;
    const ushort_t* src = (r < 16 ? wzp + (size_t)r * 4096
                                  : whp + (size_t)(r - 16) * 4096) + cc * 8;
    __builtin_amdgcn_global_load_lds((gv_t*)src, (lv_t*)(lds + idx * 8), 16, 0, 0);
  }

  f4v accz[4][2], acch[4][2];
#pragma unroll
  for (int i = 0; i < 4; i++)
#pragma unroll
    for (int jj = 0; jj < 2; jj++) {
      accz[i][jj] = (f4v){0.f, 0.f, 0.f, 0.f};
      acch[i][jj] = (f4v){0.f, 0.f, 0.f, 0.f};
    }

  int rw = mt * 8 + wr;                         // global chunk id R [0,512)
  int rt = rw >> 1, half = rw & 1;              // Xb 128-row tile, half select
  const s8v* xs = reinterpret_cast<const s8v*>(Xb) + (size_t)rt * 16 * 512 + (half * 4) * 64 + lane;
  const ushort_t* lz = lds;                     // ds offsets fit 16-bit with 2 bases
  const ushort_t* lh = lds + 32768;
  int cb0 = (wc * 2) * 64 + lane;               // col-chunk base within region

  __syncthreads();                              // W resident; read-only hereafter

  auto ldX = [&](s8v* A, int kt) {
#pragma unroll
    for (int i = 0; i < 4; i++) A[i] = xs[kt * 512 + i * 64];
  };
  auto step = [&](int kt, s8v* A) {
    s8v bz[2], bh[2];
#pragma unroll
    for (int jj = 0; jj < 2; jj++) {
      bz[jj] = *reinterpret_cast<const s8v*>(lz + (size_t)kt * 2048 + (size_t)(cb0 + jj * 64) * 8);
      bh[jj] = *reinterpret_cast<const s8v*>(lh + (size_t)kt * 2048 + (size_t)(cb0 + jj * 64) * 8);
    }
#pragma unroll
    for (int i = 0; i < 4; i++)
#pragma unroll
      for (int jj = 0; jj < 2; jj++) {
        accz[i][jj] = __builtin_amdgcn_mfma_f32_16x16x32_bf16(A[i], bz[jj], accz[i][jj], 0, 0, 0);
        acch[i][jj] = __builtin_amdgcn_mfma_f32_16x16x32_bf16(A[i], bh[jj], acch[i][jj], 0, 0, 0);
      }
  };

  // 2-slot static X prefetch (rule #20: all indices compile-time)
  s8v A0[4], A1[4];
  ldX(A0, 0); ldX(A1, 1);
#pragma unroll
  for (int kp = 0; kp < 8; kp++) {
    step(2 * kp, A0);
    if (kp < 7) ldX(A0, 2 * kp + 2);
    step(2 * kp + 1, A1);
    if (kp < 7) ldX(A1, 2 * kp + 3);
  }

  // ---- epilogue: C/D layout col=lane&15, row=(lane>>4)*4+q  [m89/m91] ----
  int R = rw, Cc = p;
  size_t base = (size_t)(R * 8 + Cc) * 1024;
  float bzv[2], bhv[2];
#pragma unroll
  for (int jj = 0; jj < 2; jj++) {
    int h = p * 64 + (wc * 2 + jj) * 16 + (lane & 15);
    bzv[jj] = bzp[h];
    bhv[jj] = bhp[h];
  }
  float QA[4][2], QB[4][2];   // per-(i,jj) 4-t composites from ROUNDED fp16 a,b
#pragma unroll
  for (int i = 0; i < 4; i++)
#pragma unroll
    for (int jj = 0; jj < 2; jj++) {
      h8v g;
      float Pa = 1.f, Pb = 0.f;
#pragma unroll
      for (int q = 0; q < 4; q++) {
        float z = 1.f / (1.f + __expf(-(accz[i][jj][q] + bzv[jj])));
        float e = __expf(2.f * (acch[i][jj][q] + bhv[jj]));
        float th = 1.f - 2.f / (e + 1.f);
        g[q] = (_Float16)(1.f - z);        // a_t
        g[4 + q] = (_Float16)(z * th);     // b_t
        float a = (float)g[q], b = (float)g[4 + q];
        Pa = a * Pa;                        // t ascending within lane (q)
        Pb = a * Pb + b;
      }
      cab[base + (size_t)((i * 4 + wc * 2 + jj) * 64 + lane)] = g;
      QA[i][jj] = Pa;
      QB[i][jj] = Pb;
    }

  // fused chunk summary: compose over lane-groups g=(lane>>4) then i, per jj.
#pragma unroll
  for (int jj = 0; jj < 2; jj++) {
    float A = 1.f, Bv = 0.f;
#pragma unroll
    for (int i = 0; i < 4; i++) {
      float a = QA[i][jj], b = QB[i][jj];
      float ap = __shfl_xor(a, 16), bp = __shfl_xor(b, 16);
      bool hi = (lane & 16) != 0;
      float af_ = hi ? ap : a, bf_ = hi ? bp : b;   // earlier segment
      float as_ = hi ? a : ap, bs_ = hi ? b : bp;   // later segment
      a = as_ * af_; b = as_ * bf_ + bs_;
      ap = __shfl_xor(a, 32); bp = __shfl_xor(b, 32);
      bool hi2 = (lane & 32) != 0;
      af_ = hi2 ? ap : a; bf_ = hi2 ? bp : b;
      as_ = hi2 ? a : ap; bs_ = hi2 ? b : bp;
      a = as_ * af_; b = as_ * bf_ + bs_;
      Bv = a * Bv + b;
      A = a * A;
    }
    if (lane < 16) {
      int h = p * 64 + (wc * 2 + jj) * 16 + lane;
      cA[(size_t)R * Hn + h] = A;
      cB[(size_t)R * Hn + h] = Bv;
    }
  }
}

// S2: serial scan over 64 chunk summaries per (b,h) -> h_start per chunk
__global__ __launch_bounds__(256) void scan_heads(
    const float* __restrict__ cA, const float* __restrict__ cB,
    const float* __restrict__ h0p, float* __restrict__ hst) {
  int gid = blockIdx.x * 256 + threadIdx.x;   // 4096 = B*H
  int b = gid >> 9, h = gid & 511;
  float hr = h0p[(size_t)b * Hn + h];
#pragma unroll 8
  for (int c = 0; c < NC; c++) {
    size_t o = (size_t)(b * NC + c) * Hn + h;
    hst[o] = hr;
    hr = fmaf(cA[o], hr, cB[o]);
  }
}

// S3: replay each chunk from its h_start, write fp32 outputs (B,T,H)
__global__ __launch_bounds__(256) void scan_apply(
    const h8v* __restrict__ cab, const float* __restrict__ hst,
    float* __restrict__ out) {
  int h = blockIdx.y * 256 + threadIdx.x;
  int R = blockIdx.x;
  int hl = h & 63, Cc = h >> 6;
  size_t base = (size_t)(R * 8 + Cc) * 1024 + (size_t)(hl >> 4) * 64 + (hl & 15);
  float hr = hst[(size_t)R * Hn + h];
  size_t ob = (size_t)R * 64 * Hn + h;
#pragma unroll
  for (int i = 0; i < 4; i++)
#pragma unroll
    for (int p = 0; p < 4; p++) {
      h8v g = cab[base + i * 256 + p * 16];
#pragma unroll
      for (int q = 0; q < 4; q++) {
        hr = fmaf((float)g[q], hr, (float)g[4 + q]);
        out[ob + (size_t)(i * 16 + p * 4 + q) * Hn] = hr;
      }
    }
}

extern "C" void kernel_launch(void* const* d_in, const int* in_sizes, int n_in,
                              void* d_out, int out_size, void* d_ws, size_t ws_size,
                              hipStream_t stream) {
  const float* X   = (const float*)d_in[0];
  const float* h0p = (const float*)d_in[1];
  const float* Wz  = (const float*)d_in[2];
  const float* bz  = (const float*)d_in[3];
  const float* Wh  = (const float*)d_in[4];
  const float* bh  = (const float*)d_in[5];
  float* out = (float*)d_out;

  char* ws = (char*)d_ws;
  ushort_t* Xb  = (ushort_t*)ws;                                  // 33.6 MB
  ushort_t* Wzb = Xb + (size_t)Mn * Dn;                           // 0.5 MB
  ushort_t* Whb = Wzb + (size_t)Hn * Dn;                          // 0.5 MB
  h8v* cab      = (h8v*)(Whb + (size_t)Hn * Dn);                  // 67.1 MB
  // cab = 2*Mn*Hn halves = Mn*Hn/4 granules of 16B
  float* cA     = (float*)(cab + (size_t)Mn * Hn / 4);            // 1 MB
  float* cB     = cA + (size_t)Bn * NC * Hn;                      // 1 MB
  float* hst    = cB + (size_t)Bn * NC * Hn;                      // 1 MB

  convert_x<<<dim3(4096), 256, 0, stream>>>(X, Xb);
  convert_w<<<dim3(128), 256, 0, stream>>>(Wz, Wh, Wzb, Whb);

  gemm_act<<<dim3(512), 1024, 0, stream>>>(Xb, Wzb, Whb, bz, bh, cab, cA, cB);

  scan_heads<<<dim3(Bn * Hn / 256), 256, 0, stream>>>(cA, cB, h0p, hst);
  scan_apply<<<dim3(Mn / 64, Hn / 256), 256, 0, stream>>>(cab, hst, out);
}

// Round 14
// 99.762 us; speedup vs baseline: 1.0207x; 1.0207x over previous
//
#include <hip/hip_runtime.h>

constexpr int Bn = 8, Tn = 4096, Dn = 512, Hn = 512;
constexpr int Mn = Bn * Tn;            // 32768 rows
constexpr int CH = 64, NC = Tn / CH;   // 64 chunks of 64 steps

typedef __attribute__((ext_vector_type(8))) short s8v;       // 8 bf16
typedef __attribute__((ext_vector_type(4))) float f4v;       // MFMA acc
typedef __attribute__((ext_vector_type(8))) _Float16 h8v;    // 16B granule: a[0..3], b[0..3]
typedef unsigned short ushort_t;

typedef __attribute__((address_space(1))) const void gv_t;   // global src for load_lds
typedef __attribute__((address_space(3))) void lv_t;         // LDS dst for load_lds

__device__ __forceinline__ short f2bf(float f) {
  unsigned u = __float_as_uint(f);
  u = (u + 0x7fffu + ((u >> 16) & 1u)) >> 16;   // RNE
  return (short)u;
}

// fp32 [rows][512] -> bf16 tiles of 128 rows x 32 k in MFMA-fragment order.
// Tile lb = rt*16 + kt; chunk c = (r>>4)*64 + k8*16 + (r&15), 16B each.
__global__ __launch_bounds__(256) void convert_x(
    const float* __restrict__ X, ushort_t* __restrict__ Xb) {
  int lb = blockIdx.x, tid = threadIdx.x;
  const float* tsrc = X + ((size_t)(lb >> 4) * 128) * Dn + (lb & 15) * 32;
#pragma unroll
  for (int p = 0; p < 2; p++) {
    int idx = tid + p * 256;
    int r = idx >> 2, k8 = idx & 3;
    const float4* sv = reinterpret_cast<const float4*>(tsrc + (size_t)r * Dn + k8 * 8);
    float4 f0 = sv[0], f1 = sv[1];
    s8v v;
    v[0] = f2bf(f0.x); v[1] = f2bf(f0.y); v[2] = f2bf(f0.z); v[3] = f2bf(f0.w);
    v[4] = f2bf(f1.x); v[5] = f2bf(f1.y); v[6] = f2bf(f1.z); v[7] = f2bf(f1.w);
    int c = (r >> 4) * 64 + k8 * 16 + (r & 15);
    *reinterpret_cast<s8v*>(&Xb[((size_t)lb * 512 + c) * 8]) = v;
  }
}

// Same for W. Blocks [0,64) = Wz, [64,128) = Wh.
__global__ __launch_bounds__(256) void convert_w(
    const float* __restrict__ Wz, const float* __restrict__ Wh,
    ushort_t* __restrict__ Wzb, ushort_t* __restrict__ Whb) {
  int bx = blockIdx.x, tid = threadIdx.x;
  const float* src;
  ushort_t* dst;
  int lb;
  if (bx < 64) { src = Wz; dst = Wzb; lb = bx; }
  else         { src = Wh; dst = Whb; lb = bx - 64; }
  const float* tsrc = src + ((size_t)(lb >> 4) * 128) * Dn + (lb & 15) * 32;
#pragma unroll
  for (int p = 0; p < 2; p++) {
    int idx = tid + p * 256;
    int r = idx >> 2, k8 = idx & 3;
    const float4* sv = reinterpret_cast<const float4*>(tsrc + (size_t)r * Dn + k8 * 8);
    float4 f0 = sv[0], f1 = sv[1];
    s8v v;
    v[0] = f2bf(f0.x); v[1] = f2bf(f0.y); v[2] = f2bf(f0.z); v[3] = f2bf(f0.w);
    v[4] = f2bf(f1.x); v[5] = f2bf(f1.y); v[6] = f2bf(f1.z); v[7] = f2bf(f1.w);
    int c = (r >> 4) * 64 + k8 * 16 + (r & 15);
    *reinterpret_cast<s8v*>(&dst[((size_t)lb * 512 + c) * 8]) = v;
  }
}

// Phased dual GEMM (m201-style): block = 256 M-rows x 128 h-cols DUAL, B
// panel = [Wz;Wh] stacked (256 cols). 8 waves (2 row x 4 col-groups); each
// wave computes 128x64 of ONE matrix (acc=128 regs). BK=64, double-buffered
// 128KB LDS staged via global_load_lds (linear dst == fragment order ->
// conflict-free). Per tile: 4 phases {certify vmcnt(4) -> ds_read 4-8 ->
// stage 2 loads of next tile's half -> barrier -> lgkm0 -> setprio MFMA 16}.
// vmcnt never drains to 0 in-loop. Epilogue: z/h wave pairs exchange acc
// halves through freed LDS, then granules + chunk summaries.
__global__ __launch_bounds__(512, 2) void gemm_act(
    const ushort_t* __restrict__ Xb, const ushort_t* __restrict__ Wzb,
    const ushort_t* __restrict__ Whb,
    const float* __restrict__ bzp, const float* __restrict__ bhp,
    h8v* __restrict__ cab, float* __restrict__ cA, float* __restrict__ cB) {
  __shared__ __align__(16) ushort_t lds[65536];   // 128 KB: A dbuf 64K | B dbuf 64K

  int tid = threadIdx.x, lane = tid & 63, wid = tid >> 6;
  int wr = wid >> 2;                    // row group (128 rows)
  int wc = wid & 3;                     // col group: 0,1 = Wz; 2,3 = Wh
  int is_h = wc >> 1, c01 = wc & 1;

  // XCD swizzle (512 % 8 == 0, bijective); same-XCD neighbors share bm (A panel)
  int o = blockIdx.x;
  int wg = (o & 7) * 64 + (o >> 3);
  int bm = wg >> 2;                     // [0,128) 256-row tile
  int bh = wg & 3;                      // [0,4)   128-hcol panel

  // LDS ushort-index map: A buf b region (k2,r2) @ b*16384 + (k2*2+r2)*4096
  //                       B buf b region (k2,m)  @ 32768 + b*16384 + (k2*2+m)*4096
  auto stageHalf = [&](int b, int ks, int half) {
    int k2 = half >> 1;
    int kt = ks * 2 + k2;
    if ((half & 1) == 0) {
#pragma unroll
      for (int r2 = 0; r2 < 2; r2++) {
        const ushort_t* s = Xb + ((size_t)((bm * 2 + r2) * 16 + kt)) * 4096 + tid * 8;
        __builtin_amdgcn_global_load_lds(
            (gv_t*)s, (lv_t*)(lds + b * 16384 + (k2 * 2 + r2) * 4096 + tid * 8), 16, 0, 0);
      }
    } else {
#pragma unroll
      for (int m = 0; m < 2; m++) {
        const ushort_t* s = (m ? Whb : Wzb) + ((size_t)(bh * 16 + kt)) * 4096 + tid * 8;
        __builtin_amdgcn_global_load_lds(
            (gv_t*)s, (lv_t*)(lds + 32768 + b * 16384 + (k2 * 2 + m) * 4096 + tid * 8), 16, 0, 0);
      }
    }
  };

  f4v acc[8][4];
#pragma unroll
  for (int i = 0; i < 8; i++)
#pragma unroll
    for (int j = 0; j < 4; j++) acc[i][j] = (f4v){0.f, 0.f, 0.f, 0.f};

  // prologue: stage tile 0 fully (8 loads)
#pragma unroll
  for (int h = 0; h < 4; h++) stageHalf(0, 0, h);

  int cur = 0;
  for (int ks = 0; ks < 8; ks++) {
    s8v Bf[4];
#pragma unroll
    for (int q = 0; q < 4; q++) {
      constexpr int K2[4] = {0, 0, 1, 1};
      constexpr int IH[4] = {0, 1, 0, 1};
      int k2 = K2[q];
      // certify: even phases guarantee this k2's halves landed (all waves, via barrier)
      if (q == 0) {
        asm volatile("s_waitcnt vmcnt(4)" ::: "memory");
        __builtin_amdgcn_sched_barrier(0);
        __builtin_amdgcn_s_barrier();
      } else if (q == 2) {
        if (ks == 7) asm volatile("s_waitcnt vmcnt(0)" ::: "memory");
        else         asm volatile("s_waitcnt vmcnt(4)" ::: "memory");
        __builtin_amdgcn_sched_barrier(0);
        __builtin_amdgcn_s_barrier();
      }
      // ds-load register subtile
      s8v Af[4];
#pragma unroll
      for (int ii = 0; ii < 4; ii++) {
        int g = IH[q] * 4 + ii;
        Af[ii] = *reinterpret_cast<const s8v*>(
            lds + cur * 16384 + (k2 * 2 + wr) * 4096 + (g * 64 + lane) * 8);
      }
      if (IH[q] == 0) {
#pragma unroll
        for (int j = 0; j < 4; j++) {
          int gj = c01 * 4 + j;
          Bf[j] = *reinterpret_cast<const s8v*>(
              lds + 32768 + cur * 16384 + (k2 * 2 + is_h) * 4096 + (gj * 64 + lane) * 8);
        }
      }
      // stage next tile's half q
      if (ks + 1 < 8) stageHalf(cur ^ 1, ks + 1, q);
      asm volatile("s_waitcnt lgkmcnt(0)" ::: "memory");
      __builtin_amdgcn_sched_barrier(0);
      __builtin_amdgcn_s_setprio(1);
#pragma unroll
      for (int ii = 0; ii < 4; ii++)
#pragma unroll
        for (int j = 0; j < 4; j++)
          acc[IH[q] * 4 + ii][j] =
              __builtin_amdgcn_mfma_f32_16x16x32_bf16(Af[ii], Bf[j], acc[IH[q] * 4 + ii][j], 0, 0, 0);
      __builtin_amdgcn_s_setprio(0);
      __builtin_amdgcn_sched_barrier(0);
      __builtin_amdgcn_s_barrier();
    }
    cur ^= 1;
  }

  // ---- epilogue: exchange partner-matrix acc halves through LDS ----
  __syncthreads();                      // LDS free for reuse
  f4v* ex = reinterpret_cast<f4v*>(lds);
  size_t slot = (size_t)wid * 1024;     // 16KB per wave (1024 f4v)
  if (!is_h) {
#pragma unroll
    for (int i = 0; i < 4; i++)
#pragma unroll
      for (int j = 0; j < 4; j++) ex[slot + (i * 4 + j) * 64 + lane] = acc[i + 4][j];
  } else {
#pragma unroll
    for (int i = 0; i < 4; i++)
#pragma unroll
      for (int j = 0; j < 4; j++) ex[slot + (i * 4 + j) * 64 + lane] = acc[i][j];
  }
  __syncthreads();
  size_t pslot = (size_t)(wid ^ 2) * 1024;

  // C/D layout col=lane&15, row=(lane>>4)*4+q  [m89/m91]
  int R = bm * 4 + wr * 2 + is_h;       // global chunk id
  int Cc = bh * 2 + c01;
  size_t base = (size_t)(R * 8 + Cc) * 1024;
  float bzv[4], bhv[4];
#pragma unroll
  for (int j = 0; j < 4; j++) {
    int h = bh * 128 + c01 * 64 + j * 16 + (lane & 15);
    bzv[j] = bzp[h];
    bhv[j] = bhp[h];
  }
  float QA[4][4], QB[4][4];   // per-(i,j) 4-t composites from ROUNDED fp16 a,b
#pragma unroll
  for (int i = 0; i < 4; i++)
#pragma unroll
    for (int j = 0; j < 4; j++) {
      f4v other = ex[pslot + (i * 4 + j) * 64 + lane];
      f4v vz4, vh4;
      if (!is_h) { vz4 = acc[i][j]; vh4 = other; }
      else       { vz4 = other;     vh4 = acc[i + 4][j]; }
      h8v g;
      float Pa = 1.f, Pb = 0.f;
#pragma unroll
      for (int q = 0; q < 4; q++) {
        float z = 1.f / (1.f + __expf(-(vz4[q] + bzv[j])));
        float e = __expf(2.f * (vh4[q] + bhv[j]));
        float th = 1.f - 2.f / (e + 1.f);
        g[q] = (_Float16)(1.f - z);        // a_t
        g[4 + q] = (_Float16)(z * th);     // b_t
        float a = (float)g[q], b = (float)g[4 + q];
        Pa = a * Pa;                        // t ascending within lane (q)
        Pb = a * Pb + b;
      }
      cab[base + (size_t)((i * 4 + j) * 64 + lane)] = g;
      QA[i][j] = Pa;
      QB[i][j] = Pb;
    }

  // fused chunk summary: compose over lane-groups g=(lane>>4) then i, per j.
#pragma unroll
  for (int j = 0; j < 4; j++) {
    float A = 1.f, Bv = 0.f;
#pragma unroll
    for (int i = 0; i < 4; i++) {
      float a = QA[i][j], b = QB[i][j];
      float ap = __shfl_xor(a, 16), bp = __shfl_xor(b, 16);
      bool hi = (lane & 16) != 0;
      float af_ = hi ? ap : a, bf_ = hi ? bp : b;   // earlier segment
      float as_ = hi ? a : ap, bs_ = hi ? b : bp;   // later segment
      a = as_ * af_; b = as_ * bf_ + bs_;
      ap = __shfl_xor(a, 32); bp = __shfl_xor(b, 32);
      bool hi2 = (lane & 32) != 0;
      af_ = hi2 ? ap : a; bf_ = hi2 ? bp : b;
      as_ = hi2 ? a : ap; bs_ = hi2 ? b : bp;
      a = as_ * af_; b = as_ * bf_ + bs_;
      Bv = a * Bv + b;
      A = a * A;
    }
    if (lane < 16) {
      int h = bh * 128 + c01 * 64 + j * 16 + lane;
      cA[(size_t)R * Hn + h] = A;
      cB[(size_t)R * Hn + h] = Bv;
    }
  }
}

// S2: serial scan over 64 chunk summaries per (b,h) -> h_start per chunk
__global__ __launch_bounds__(256) void scan_heads(
    const float* __restrict__ cA, const float* __restrict__ cB,
    const float* __restrict__ h0p, float* __restrict__ hst) {
  int gid = blockIdx.x * 256 + threadIdx.x;   // 4096 = B*H
  int b = gid >> 9, h = gid & 511;
  float hr = h0p[(size_t)b * Hn + h];
#pragma unroll 8
  for (int c = 0; c < NC; c++) {
    size_t o = (size_t)(b * NC + c) * Hn + h;
    hst[o] = hr;
    hr = fmaf(cA[o], hr, cB[o]);
  }
}

// S3: replay each chunk from its h_start, write fp32 outputs (B,T,H)
__global__ __launch_bounds__(256) void scan_apply(
    const h8v* __restrict__ cab, const float* __restrict__ hst,
    float* __restrict__ out) {
  int h = blockIdx.y * 256 + threadIdx.x;
  int R = blockIdx.x;
  int hl = h & 63, Cc = h >> 6;
  size_t base = (size_t)(R * 8 + Cc) * 1024 + (size_t)(hl >> 4) * 64 + (hl & 15);
  float hr = hst[(size_t)R * Hn + h];
  size_t ob = (size_t)R * 64 * Hn + h;
#pragma unroll
  for (int i = 0; i < 4; i++)
#pragma unroll
    for (int p = 0; p < 4; p++) {
      h8v g = cab[base + i * 256 + p * 16];
#pragma unroll
      for (int q = 0; q < 4; q++) {
        hr = fmaf((float)g[q], hr, (float)g[4 + q]);
        out[ob + (size_t)(i * 16 + p * 4 + q) * Hn] = hr;
      }
    }
}

extern "C" void kernel_launch(void* const* d_in, const int* in_sizes, int n_in,
                              void* d_out, int out_size, void* d_ws, size_t ws_size,
                              hipStream_t stream) {
  const float* X   = (const float*)d_in[0];
  const float* h0p = (const float*)d_in[1];
  const float* Wz  = (const float*)d_in[2];
  const float* bz  = (const float*)d_in[3];
  const float* Wh  = (const float*)d_in[4];
  const float* bh  = (const float*)d_in[5];
  float* out = (float*)d_out;

  char* ws = (char*)d_ws;
  ushort_t* Xb  = (ushort_t*)ws;                                  // 33.6 MB
  ushort_t* Wzb = Xb + (size_t)Mn * Dn;                           // 0.5 MB
  ushort_t* Whb = Wzb + (size_t)Hn * Dn;                          // 0.5 MB
  h8v* cab      = (h8v*)(Whb + (size_t)Hn * Dn);                  // 67.1 MB
  // cab = 2*Mn*Hn halves = Mn*Hn/4 granules of 16B
  float* cA     = (float*)(cab + (size_t)Mn * Hn / 4);            // 1 MB
  float* cB     = cA + (size_t)Bn * NC * Hn;                      // 1 MB
  float* hst    = cB + (size_t)Bn * NC * Hn;                      // 1 MB

  convert_x<<<dim3(4096), 256, 0, stream>>>(X, Xb);
  convert_w<<<dim3(128), 256, 0, stream>>>(Wz, Wh, Wzb, Whb);

  gemm_act<<<dim3(512), 512, 0, stream>>>(Xb, Wzb, Whb, bz, bh, cab, cA, cB);

  scan_heads<<<dim3(Bn * Hn / 256), 256, 0, stream>>>(cA, cB, h0p, hst);
  scan_apply<<<dim3(Mn / 64, Hn / 256), 256, 0, stream>>>(cab, hst, out);
}

// Round 15
// 93.899 us; speedup vs baseline: 1.0844x; 1.0624x over previous
//
#include <hip/hip_runtime.h>

constexpr int Bn = 8, Tn = 4096, Dn = 512, Hn = 512;
constexpr int Mn = Bn * Tn;            // 32768 rows
constexpr int CH = 64, NC = Tn / CH;   // 64 chunks of 64 steps

typedef __attribute__((ext_vector_type(8))) short s8v;       // 8 bf16
typedef __attribute__((ext_vector_type(4))) float f4v;       // MFMA acc
typedef __attribute__((ext_vector_type(8))) _Float16 h8v;    // 16B granule: a[0..3], b[0..3]
typedef unsigned short ushort_t;

typedef __attribute__((address_space(1))) const void gv_t;   // global src for load_lds
typedef __attribute__((address_space(3))) void lv_t;         // LDS dst for load_lds

__device__ __forceinline__ short f2bf(float f) {
  unsigned u = __float_as_uint(f);
  u = (u + 0x7fffu + ((u >> 16) & 1u)) >> 16;   // RNE
  return (short)u;
}

// fp32 [rows][512] -> bf16 tiles of 128 rows x 32 k in MFMA-fragment order.
// Tile lb = rt*16 + kt; chunk c = (r>>4)*64 + k8*16 + (r&15), 16B each.
// Blocks [0,4096) = X; [4096,4160) = Wz; [4160,4224) = Wh (merged launch).
__global__ __launch_bounds__(256) void convert_all(
    const float* __restrict__ X, const float* __restrict__ Wz,
    const float* __restrict__ Wh, ushort_t* __restrict__ Xb,
    ushort_t* __restrict__ Wzb, ushort_t* __restrict__ Whb) {
  int bx = blockIdx.x, tid = threadIdx.x;
  const float* src;
  ushort_t* dst;
  int lb;
  if (bx < 4096)      { src = X;  dst = Xb;  lb = bx; }
  else if (bx < 4160) { src = Wz; dst = Wzb; lb = bx - 4096; }
  else                { src = Wh; dst = Whb; lb = bx - 4160; }
  const float* tsrc = src + ((size_t)(lb >> 4) * 128) * Dn + (lb & 15) * 32;
#pragma unroll
  for (int p = 0; p < 2; p++) {
    int idx = tid + p * 256;
    int r = idx >> 2, k8 = idx & 3;
    const float4* sv = reinterpret_cast<const float4*>(tsrc + (size_t)r * Dn + k8 * 8);
    float4 f0 = sv[0], f1 = sv[1];
    s8v v;
    v[0] = f2bf(f0.x); v[1] = f2bf(f0.y); v[2] = f2bf(f0.z); v[3] = f2bf(f0.w);
    v[4] = f2bf(f1.x); v[5] = f2bf(f1.y); v[6] = f2bf(f1.z); v[7] = f2bf(f1.w);
    int c = (r >> 4) * 64 + k8 * 16 + (r & 15);
    *reinterpret_cast<s8v*>(&dst[((size_t)lb * 512 + c) * 8]) = v;
  }
}

// W-stationary barrier-free dual GEMM + activations + chunk summaries.
// (round-9 best: 54.6-54.8 us, MfmaUtil ~26%, 0 bank conflicts)
// Block = (mt, p): 512 M-rows x 64 H-cols. Stages panel p's FULL W_z,W_h
// (K=512) into 128KB LDS once (1 barrier total), then K-loop with no
// barriers: W via broadcast ds_read, X reg-direct from pre-swizzled Xb
// (2-deep manual prefetch). 8 waves; wave = 64 rows (one chunk) x 64 cols.
__global__ __launch_bounds__(512, 2) void gemm_act(
    const ushort_t* __restrict__ Xb, const ushort_t* __restrict__ Wzb,
    const ushort_t* __restrict__ Whb,
    const float* __restrict__ bzp, const float* __restrict__ bhp,
    h8v* __restrict__ cab, float* __restrict__ cA, float* __restrict__ cB) {
  __shared__ __align__(16) ushort_t lds[32 * 2048];   // 32 regions x 4KB = 128KB

  int tid = threadIdx.x, lane = tid & 63, wid = tid >> 6;

  // XCD-affinity: XCD x owns mt in [8x, 8x+8); 8 panels of one mt adjacent.
  int o = blockIdx.x;
  int loc = o >> 3;
  int mt = (o & 7) * 8 + (loc >> 3);            // [0,64)  M-tile of 512 rows
  int p = loc & 7;                              // [0,8)   64-col H-panel

  // ---- stage W panel: region r = m*16+kt (m: 0=Wz,1=Wh), 4KB each ----
#pragma unroll
  for (int q = 0; q < 16; q++) {
    int r = q * 2 + (wid >> 2);                 // wave-uniform region id
    int kt = r & 15;
    const ushort_t* wsrc = (r >= 16 ? Whb : Wzb);
    const ushort_t* s = wsrc + ((size_t)((p >> 1) * 16 + kt)) * 4096 + (p & 1) * 2048 + (tid & 255) * 8;
    __builtin_amdgcn_global_load_lds((gv_t*)s, (lv_t*)(lds + r * 2048 + (tid & 255) * 8), 16, 0, 0);
  }

  f4v accz[4][4], acch[4][4];
#pragma unroll
  for (int i = 0; i < 4; i++)
#pragma unroll
    for (int j = 0; j < 4; j++) {
      accz[i][j] = (f4v){0.f, 0.f, 0.f, 0.f};
      acch[i][j] = (f4v){0.f, 0.f, 0.f, 0.f};
    }

  int rw = mt * 8 + wid;                        // global chunk id R [0,512)
  int rt = rw >> 1, half = rw & 1;              // Xb 128-row tile, half select
  const ushort_t* xb = Xb + (size_t)rt * 16 * 4096;

  __syncthreads();                              // W resident; read-only hereafter

  auto ldW = [&](int kt, s8v* bzf, s8v* bhf) {
#pragma unroll
    for (int j = 0; j < 4; j++) {
      bzf[j] = *reinterpret_cast<const s8v*>(lds + (size_t)kt * 2048 + (j * 64 + lane) * 8);
      bhf[j] = *reinterpret_cast<const s8v*>(lds + (size_t)(16 + kt) * 2048 + (j * 64 + lane) * 8);
    }
  };
  auto mfmaStep = [&](s8v* af, s8v* bzf, s8v* bhf) {
    __builtin_amdgcn_s_setprio(1);
#pragma unroll
    for (int i = 0; i < 4; i++)
#pragma unroll
      for (int j = 0; j < 4; j++) {
        accz[i][j] = __builtin_amdgcn_mfma_f32_16x16x32_bf16(af[i], bzf[j], accz[i][j], 0, 0, 0);
        acch[i][j] = __builtin_amdgcn_mfma_f32_16x16x32_bf16(af[i], bhf[j], acch[i][j], 0, 0, 0);
      }
    __builtin_amdgcn_s_setprio(0);
  };

  s8v afA[4], afB[4];
#pragma unroll
  for (int i = 0; i < 4; i++)
    afA[i] = *reinterpret_cast<const s8v*>(xb + ((half * 4 + i) * 64 + lane) * 8);

#pragma unroll
  for (int kp = 0; kp < 8; kp++) {
    int k0 = 2 * kp;
#pragma unroll
    for (int i = 0; i < 4; i++)
      afB[i] = *reinterpret_cast<const s8v*>(xb + (size_t)(k0 + 1) * 4096 + ((half * 4 + i) * 64 + lane) * 8);
    s8v bz0[4], bh0[4];
    ldW(k0, bz0, bh0);
    mfmaStep(afA, bz0, bh0);
    if (k0 + 2 < 16) {
#pragma unroll
      for (int i = 0; i < 4; i++)
        afA[i] = *reinterpret_cast<const s8v*>(xb + (size_t)(k0 + 2) * 4096 + ((half * 4 + i) * 64 + lane) * 8);
    }
    s8v bz1[4], bh1[4];
    ldW(k0 + 1, bz1, bh1);
    mfmaStep(afB, bz1, bh1);
  }

  // ---- epilogue: C/D layout col=lane&15, row=(lane>>4)*4+q  [m89/m91] ----
  int R = rw, Cc = p;
  size_t base = (size_t)(R * 8 + Cc) * 1024;
  float bzv[4], bhv[4];
#pragma unroll
  for (int j = 0; j < 4; j++) {
    int h = p * 64 + j * 16 + (lane & 15);
    bzv[j] = bzp[h];
    bhv[j] = bhp[h];
  }
  float QA[4][4], QB[4][4];   // per-(i,j) 4-t composites from ROUNDED fp16 a,b
#pragma unroll
  for (int i = 0; i < 4; i++)
#pragma unroll
    for (int j = 0; j < 4; j++) {
      h8v g;
      float Pa = 1.f, Pb = 0.f;
#pragma unroll
      for (int q = 0; q < 4; q++) {
        float z = 1.f / (1.f + __expf(-(accz[i][j][q] + bzv[j])));
        float e = __expf(2.f * (acch[i][j][q] + bhv[j]));
        float th = 1.f - 2.f / (e + 1.f);
        g[q] = (_Float16)(1.f - z);        // a_t
        g[4 + q] = (_Float16)(z * th);     // b_t
        float a = (float)g[q], b = (float)g[4 + q];
        Pa = a * Pa;                        // t ascending within lane (q)
        Pb = a * Pb + b;
      }
      cab[base + (size_t)((i * 4 + j) * 64 + lane)] = g;
      QA[i][j] = Pa;
      QB[i][j] = Pb;
    }

  // fused chunk summary: compose over lane-groups g=(lane>>4) then i, per j.
#pragma unroll
  for (int j = 0; j < 4; j++) {
    float A = 1.f, Bv = 0.f;
#pragma unroll
    for (int i = 0; i < 4; i++) {
      float a = QA[i][j], b = QB[i][j];
      float ap = __shfl_xor(a, 16), bp = __shfl_xor(b, 16);
      bool hi = (lane & 16) != 0;
      float af_ = hi ? ap : a, bf_ = hi ? bp : b;   // earlier segment
      float as_ = hi ? a : ap, bs_ = hi ? b : bp;   // later segment
      a = as_ * af_; b = as_ * bf_ + bs_;
      ap = __shfl_xor(a, 32); bp = __shfl_xor(b, 32);
      bool hi2 = (lane & 32) != 0;
      af_ = hi2 ? ap : a; bf_ = hi2 ? bp : b;
      as_ = hi2 ? a : ap; bs_ = hi2 ? b : bp;
      a = as_ * af_; b = as_ * bf_ + bs_;
      Bv = a * Bv + b;
      A = a * A;
    }
    if (lane < 16) {
      int h = p * 64 + j * 16 + lane;
      cA[(size_t)R * Hn + h] = A;
      cB[(size_t)R * Hn + h] = Bv;
    }
  }
}

// S2: serial scan over 64 chunk summaries per (b,h) -> h_start per chunk
__global__ __launch_bounds__(256) void scan_heads(
    const float* __restrict__ cA, const float* __restrict__ cB,
    const float* __restrict__ h0p, float* __restrict__ hst) {
  int gid = blockIdx.x * 256 + threadIdx.x;   // 4096 = B*H
  int b = gid >> 9, h = gid & 511;
  float hr = h0p[(size_t)b * Hn + h];
#pragma unroll 8
  for (int c = 0; c < NC; c++) {
    size_t o = (size_t)(b * NC + c) * Hn + h;
    hst[o] = hr;
    hr = fmaf(cA[o], hr, cB[o]);
  }
}

// S3: replay each chunk from its h_start, write fp32 outputs (B,T,H)
__global__ __launch_bounds__(256) void scan_apply(
    const h8v* __restrict__ cab, const float* __restrict__ hst,
    float* __restrict__ out) {
  int h = blockIdx.y * 256 + threadIdx.x;
  int R = blockIdx.x;
  int hl = h & 63, Cc = h >> 6;
  size_t base = (size_t)(R * 8 + Cc) * 1024 + (size_t)(hl >> 4) * 64 + (hl & 15);
  float hr = hst[(size_t)R * Hn + h];
  size_t ob = (size_t)R * 64 * Hn + h;
#pragma unroll
  for (int i = 0; i < 4; i++)
#pragma unroll
    for (int p = 0; p < 4; p++) {
      h8v g = cab[base + i * 256 + p * 16];
#pragma unroll
      for (int q = 0; q < 4; q++) {
        hr = fmaf((float)g[q], hr, (float)g[4 + q]);
        out[ob + (size_t)(i * 16 + p * 4 + q) * Hn] = hr;
      }
    }
}

extern "C" void kernel_launch(void* const* d_in, const int* in_sizes, int n_in,
                              void* d_out, int out_size, void* d_ws, size_t ws_size,
                              hipStream_t stream) {
  const float* X   = (const float*)d_in[0];
  const float* h0p = (const float*)d_in[1];
  const float* Wz  = (const float*)d_in[2];
  const float* bz  = (const float*)d_in[3];
  const float* Wh  = (const float*)d_in[4];
  const float* bh  = (const float*)d_in[5];
  float* out = (float*)d_out;

  char* ws = (char*)d_ws;
  ushort_t* Xb  = (ushort_t*)ws;                                  // 33.6 MB
  ushort_t* Wzb = Xb + (size_t)Mn * Dn;                           // 0.5 MB
  ushort_t* Whb = Wzb + (size_t)Hn * Dn;                          // 0.5 MB
  h8v* cab      = (h8v*)(Whb + (size_t)Hn * Dn);                  // 67.1 MB
  // cab = 2*Mn*Hn halves = Mn*Hn/4 granules of 16B
  float* cA     = (float*)(cab + (size_t)Mn * Hn / 4);            // 1 MB
  float* cB     = cA + (size_t)Bn * NC * Hn;                      // 1 MB
  float* hst    = cB + (size_t)Bn * NC * Hn;                      // 1 MB

  convert_all<<<dim3(4224), 256, 0, stream>>>(X, Wz, Wh, Xb, Wzb, Whb);

  gemm_act<<<dim3(512), 512, 0, stream>>>(Xb, Wzb, Whb, bz, bh, cab, cA, cB);

  scan_heads<<<dim3(Bn * Hn / 256), 256, 0, stream>>>(cA, cB, h0p, hst);
  scan_apply<<<dim3(Mn / 64, Hn / 256), 256, 0, stream>>>(cab, hst, out);
}

// Round 16
// 92.394 us; speedup vs baseline: 1.1021x; 1.0163x over previous
//
#include <hip/hip_runtime.h>

constexpr int Bn = 8, Tn = 4096, Dn = 512, Hn = 512;
constexpr int Mn = Bn * Tn;            // 32768 rows
constexpr int CH = 64, NC = Tn / CH;   // 64 chunks of 64 steps

typedef __attribute__((ext_vector_type(8))) short s8v;       // 8 bf16
typedef __attribute__((ext_vector_type(4))) float f4v;       // MFMA acc
typedef __attribute__((ext_vector_type(8))) _Float16 h8v;    // 16B granule: a[0..3], b[0..3]
typedef unsigned short ushort_t;

typedef __attribute__((address_space(1))) const void gv_t;   // global src for load_lds
typedef __attribute__((address_space(3))) void lv_t;         // LDS dst for load_lds

__device__ __forceinline__ short f2bf(float f) {
  unsigned u = __float_as_uint(f);
  u = (u + 0x7fffu + ((u >> 16) & 1u)) >> 16;   // RNE
  return (short)u;
}

// fp32 [rows][512] -> bf16 tiles of 128 rows x 32 k in MFMA-fragment order.
// Tile lb = rt*16 + kt; chunk c = (r>>4)*64 + k8*16 + (r&15), 16B each.
// Blocks [0,4096) = X; [4096,4160) = Wz; [4160,4224) = Wh (merged launch).
__global__ __launch_bounds__(256) void convert_all(
    const float* __restrict__ X, const float* __restrict__ Wz,
    const float* __restrict__ Wh, ushort_t* __restrict__ Xb,
    ushort_t* __restrict__ Wzb, ushort_t* __restrict__ Whb) {
  int bx = blockIdx.x, tid = threadIdx.x;
  const float* src;
  ushort_t* dst;
  int lb;
  if (bx < 4096)      { src = X;  dst = Xb;  lb = bx; }
  else if (bx < 4160) { src = Wz; dst = Wzb; lb = bx - 4096; }
  else                { src = Wh; dst = Whb; lb = bx - 4160; }
  const float* tsrc = src + ((size_t)(lb >> 4) * 128) * Dn + (lb & 15) * 32;
#pragma unroll
  for (int p = 0; p < 2; p++) {
    int idx = tid + p * 256;
    int r = idx >> 2, k8 = idx & 3;
    const float4* sv = reinterpret_cast<const float4*>(tsrc + (size_t)r * Dn + k8 * 8);
    float4 f0 = sv[0], f1 = sv[1];
    s8v v;
    v[0] = f2bf(f0.x); v[1] = f2bf(f0.y); v[2] = f2bf(f0.z); v[3] = f2bf(f0.w);
    v[4] = f2bf(f1.x); v[5] = f2bf(f1.y); v[6] = f2bf(f1.z); v[7] = f2bf(f1.w);
    int c = (r >> 4) * 64 + k8 * 16 + (r & 15);
    *reinterpret_cast<s8v*>(&dst[((size_t)lb * 512 + c) * 8]) = v;
  }
}

// W-stationary barrier-free dual GEMM + activations + chunk summaries.
// Grid 256 = 1 block/CU, single generation. Block = (mtp, p): stages panel
// p's FULL W_z,W_h (K=512, 128KB LDS) ONCE, then processes TWO 512-row
// M-tiles. Epilogue(0)'s stores drain during K-loop(1) (fire-and-forget) ->
// de-bursts the HBM write spike; W staged once, no 2nd-generation ramp.
// K-loop/epilogue identical to the r9/r15-verified path.
__global__ __launch_bounds__(512, 2) void gemm_act(
    const ushort_t* __restrict__ Xb, const ushort_t* __restrict__ Wzb,
    const ushort_t* __restrict__ Whb,
    const float* __restrict__ bzp, const float* __restrict__ bhp,
    h8v* __restrict__ cab, float* __restrict__ cA, float* __restrict__ cB) {
  __shared__ __align__(16) ushort_t lds[32 * 2048];   // 32 regions x 4KB = 128KB

  int tid = threadIdx.x, lane = tid & 63, wid = tid >> 6;

  // XCD-affinity (grid 256, o&7 = XCD): each XCD owns 4 mtp x 8 panels,
  // so one mtp's X panel is read by 8 same-XCD blocks -> L2-resident.
  int o = blockIdx.x;
  int loc = o >> 3;
  int mtp = (o & 7) * 4 + (loc >> 3);           // [0,32) pair of 512-row M-tiles
  int p = loc & 7;                              // [0,8)  64-col H-panel

  // ---- stage W panel once: region r = m*16+kt (m: 0=Wz,1=Wh), 4KB each ----
#pragma unroll
  for (int q = 0; q < 16; q++) {
    int r = q * 2 + (wid >> 2);                 // wave-uniform region id
    int kt = r & 15;
    const ushort_t* wsrc = (r >= 16 ? Whb : Wzb);
    const ushort_t* s = wsrc + ((size_t)((p >> 1) * 16 + kt)) * 4096 + (p & 1) * 2048 + (tid & 255) * 8;
    __builtin_amdgcn_global_load_lds((gv_t*)s, (lv_t*)(lds + r * 2048 + (tid & 255) * 8), 16, 0, 0);
  }
  __syncthreads();                              // W resident; read-only hereafter

  auto ldW = [&](int kt, s8v* bzf, s8v* bhf) {
#pragma unroll
    for (int j = 0; j < 4; j++) {
      bzf[j] = *reinterpret_cast<const s8v*>(lds + (size_t)kt * 2048 + (j * 64 + lane) * 8);
      bhf[j] = *reinterpret_cast<const s8v*>(lds + (size_t)(16 + kt) * 2048 + (j * 64 + lane) * 8);
    }
  };

  for (int m2 = 0; m2 < 2; m2++) {
    int mt = mtp * 2 + m2;
    int rw = mt * 8 + wid;                      // global chunk id R [0,512)
    int rt = rw >> 1, half = rw & 1;            // Xb 128-row tile, half select
    const ushort_t* xb = Xb + (size_t)rt * 16 * 4096;

    f4v accz[4][4], acch[4][4];
#pragma unroll
    for (int i = 0; i < 4; i++)
#pragma unroll
      for (int j = 0; j < 4; j++) {
        accz[i][j] = (f4v){0.f, 0.f, 0.f, 0.f};
        acch[i][j] = (f4v){0.f, 0.f, 0.f, 0.f};
      }

    auto mfmaStep = [&](s8v* af, s8v* bzf, s8v* bhf) {
      __builtin_amdgcn_s_setprio(1);
#pragma unroll
      for (int i = 0; i < 4; i++)
#pragma unroll
        for (int j = 0; j < 4; j++) {
          accz[i][j] = __builtin_amdgcn_mfma_f32_16x16x32_bf16(af[i], bzf[j], accz[i][j], 0, 0, 0);
          acch[i][j] = __builtin_amdgcn_mfma_f32_16x16x32_bf16(af[i], bhf[j], acch[i][j], 0, 0, 0);
        }
      __builtin_amdgcn_s_setprio(0);
    };

    s8v afA[4], afB[4];
#pragma unroll
    for (int i = 0; i < 4; i++)
      afA[i] = *reinterpret_cast<const s8v*>(xb + ((half * 4 + i) * 64 + lane) * 8);

#pragma unroll
    for (int kp = 0; kp < 8; kp++) {
      int k0 = 2 * kp;
#pragma unroll
      for (int i = 0; i < 4; i++)
        afB[i] = *reinterpret_cast<const s8v*>(xb + (size_t)(k0 + 1) * 4096 + ((half * 4 + i) * 64 + lane) * 8);
      s8v bz0[4], bh0[4];
      ldW(k0, bz0, bh0);
      mfmaStep(afA, bz0, bh0);
      if (k0 + 2 < 16) {
#pragma unroll
        for (int i = 0; i < 4; i++)
          afA[i] = *reinterpret_cast<const s8v*>(xb + (size_t)(k0 + 2) * 4096 + ((half * 4 + i) * 64 + lane) * 8);
      }
      s8v bz1[4], bh1[4];
      ldW(k0 + 1, bz1, bh1);
      mfmaStep(afB, bz1, bh1);
    }

    // ---- epilogue: C/D layout col=lane&15, row=(lane>>4)*4+q  [m89/m91] ----
    int R = rw, Cc = p;
    size_t base = (size_t)(R * 8 + Cc) * 1024;
    float bzv[4], bhv[4];
#pragma unroll
    for (int j = 0; j < 4; j++) {
      int h = p * 64 + j * 16 + (lane & 15);
      bzv[j] = bzp[h];
      bhv[j] = bhp[h];
    }
    float QA[4][4], QB[4][4];  // per-(i,j) 4-t composites from ROUNDED fp16 a,b
#pragma unroll
    for (int i = 0; i < 4; i++)
#pragma unroll
      for (int j = 0; j < 4; j++) {
        h8v g;
        float Pa = 1.f, Pb = 0.f;
#pragma unroll
        for (int q = 0; q < 4; q++) {
          float z = 1.f / (1.f + __expf(-(accz[i][j][q] + bzv[j])));
          float e = __expf(2.f * (acch[i][j][q] + bhv[j]));
          float th = 1.f - 2.f / (e + 1.f);
          g[q] = (_Float16)(1.f - z);        // a_t
          g[4 + q] = (_Float16)(z * th);     // b_t
          float a = (float)g[q], b = (float)g[4 + q];
          Pa = a * Pa;                        // t ascending within lane (q)
          Pb = a * Pb + b;
        }
        cab[base + (size_t)((i * 4 + j) * 64 + lane)] = g;
        QA[i][j] = Pa;
        QB[i][j] = Pb;
      }

    // fused chunk summary: compose over lane-groups g=(lane>>4) then i, per j.
#pragma unroll
    for (int j = 0; j < 4; j++) {
      float A = 1.f, Bv = 0.f;
#pragma unroll
      for (int i = 0; i < 4; i++) {
        float a = QA[i][j], b = QB[i][j];
        float ap = __shfl_xor(a, 16), bp = __shfl_xor(b, 16);
        bool hi = (lane & 16) != 0;
        float af_ = hi ? ap : a, bf_ = hi ? bp : b;   // earlier segment
        float as_ = hi ? a : ap, bs_ = hi ? b : bp;   // later segment
        a = as_ * af_; b = as_ * bf_ + bs_;
        ap = __shfl_xor(a, 32); bp = __shfl_xor(b, 32);
        bool hi2 = (lane & 32) != 0;
        af_ = hi2 ? ap : a; bf_ = hi2 ? bp : b;
        as_ = hi2 ? a : ap; bs_ = hi2 ? b : bp;
        a = as_ * af_; b = as_ * bf_ + bs_;
        Bv = a * Bv + b;
        A = a * A;
      }
      if (lane < 16) {
        int h = p * 64 + j * 16 + lane;
        cA[(size_t)R * Hn + h] = A;
        cB[(size_t)R * Hn + h] = Bv;
      }
    }
  }
}

// S2: serial scan over 64 chunk summaries per (b,h) -> h_start per chunk
__global__ __launch_bounds__(256) void scan_heads(
    const float* __restrict__ cA, const float* __restrict__ cB,
    const float* __restrict__ h0p, float* __restrict__ hst) {
  int gid = blockIdx.x * 256 + threadIdx.x;   // 4096 = B*H
  int b = gid >> 9, h = gid & 511;
  float hr = h0p[(size_t)b * Hn + h];
#pragma unroll 8
  for (int c = 0; c < NC; c++) {
    size_t o = (size_t)(b * NC + c) * Hn + h;
    hst[o] = hr;
    hr = fmaf(cA[o], hr, cB[o]);
  }
}

// S3: replay each chunk from its h_start, write fp32 outputs (B,T,H).
// `out` is write-once -> non-temporal stores (keep L3 for cab reads).
__global__ __launch_bounds__(256) void scan_apply(
    const h8v* __restrict__ cab, const float* __restrict__ hst,
    float* __restrict__ out) {
  int h = blockIdx.y * 256 + threadIdx.x;
  int R = blockIdx.x;
  int hl = h & 63, Cc = h >> 6;
  size_t base = (size_t)(R * 8 + Cc) * 1024 + (size_t)(hl >> 4) * 64 + (hl & 15);
  float hr = hst[(size_t)R * Hn + h];
  size_t ob = (size_t)R * 64 * Hn + h;
#pragma unroll
  for (int i = 0; i < 4; i++)
#pragma unroll
    for (int p = 0; p < 4; p++) {
      h8v g = cab[base + i * 256 + p * 16];
#pragma unroll
      for (int q = 0; q < 4; q++) {
        hr = fmaf((float)g[q], hr, (float)g[4 + q]);
        __builtin_nontemporal_store(hr, &out[ob + (size_t)(i * 16 + p * 4 + q) * Hn]);
      }
    }
}

extern "C" void kernel_launch(void* const* d_in, const int* in_sizes, int n_in,
                              void* d_out, int out_size, void* d_ws, size_t ws_size,
                              hipStream_t stream) {
  const float* X   = (const float*)d_in[0];
  const float* h0p = (const float*)d_in[1];
  const float* Wz  = (const float*)d_in[2];
  const float* bz  = (const float*)d_in[3];
  const float* Wh  = (const float*)d_in[4];
  const float* bh  = (const float*)d_in[5];
  float* out = (float*)d_out;

  char* ws = (char*)d_ws;
  ushort_t* Xb  = (ushort_t*)ws;                                  // 33.6 MB
  ushort_t* Wzb = Xb + (size_t)Mn * Dn;                           // 0.5 MB
  ushort_t* Whb = Wzb + (size_t)Hn * Dn;                          // 0.5 MB
  h8v* cab      = (h8v*)(Whb + (size_t)Hn * Dn);                  // 67.1 MB
  // cab = 2*Mn*Hn halves = Mn*Hn/4 granules of 16B
  float* cA     = (float*)(cab + (size_t)Mn * Hn / 4);            // 1 MB
  float* cB     = cA + (size_t)Bn * NC * Hn;                      // 1 MB
  float* hst    = cB + (size_t)Bn * NC * Hn;                      // 1 MB

  convert_all<<<dim3(4224), 256, 0, stream>>>(X, Wz, Wh, Xb, Wzb, Whb);

  gemm_act<<<dim3(256), 512, 0, stream>>>(Xb, Wzb, Whb, bz, bh, cab, cA, cB);

  scan_heads<<<dim3(Bn * Hn / 256), 256, 0, stream>>>(cA, cB, h0p, hst);
  scan_apply<<<dim3(Mn / 64, Hn / 256), 256, 0, stream>>>(cab, hst, out);
}